// Round 21
// baseline (568.658 us; speedup 1.0000x reference)
//
#include <hip/hip_runtime.h>
#include <math.h>

#define N     50000
#define F_IN  128
#define HID   256
#define E     800000
#define OUTD  64
#define NEG   0.2f
#define N8    (N * 8)
#define NTOT  (4 * N)
#define FB    ((N + 63) / 64)        // 782 64-row blocks (final)
#define SMQ   98                     // semscore row-blocks per matrix (98*512 >= N)
#define PJQ   196                    // proj row-blocks per side (196*256 >= N)

// bucket sort geometry (fixed-capacity buckets)
#define BSH   7
#define NBUK  ((N + 127) / 128)      // 391
#define NBT   (4 * NBUK)             // 1564
#define BCAP  2560                   // Poisson(2048) + 11 sigma headroom
#define EPB1  8192
#define NB1   ((E + EPB1 - 1) / EPB1) // 98

typedef float4 f4;
typedef unsigned int u32;
typedef unsigned short ush;
typedef float f32x4 __attribute__((ext_vector_type(4)));
typedef short bf16x8 __attribute__((ext_vector_type(8)));

static __device__ __forceinline__ float lrelu(float x) { return x >= 0.f ? x : NEG * x; }
static __device__ __forceinline__ u32 bfr(float x) {
  u32 u = __float_as_uint(x);
  return (u + 0x7fffu + ((u >> 16) & 1u)) >> 16;
}
static __device__ __forceinline__ u32 pk2(float a, float b) { return bfr(a) | (bfr(b) << 16); }
static __device__ __forceinline__ float bf2f(u32 us) { return __uint_as_float(us << 16); }
static __device__ __forceinline__ float tanh_fast(float x) {
  float e = __expf(2.f * x);
  return fmaf(-2.f, __builtin_amdgcn_rcpf(e + 1.f), 1.f);
}

typedef const __attribute__((address_space(1))) unsigned int gu32;
typedef __attribute__((address_space(3))) unsigned int lu32;
static __device__ __forceinline__ void gll16(const void* g, void* l) {
  __builtin_amdgcn_global_load_lds((gu32*)g, (lu32*)l, 16, 0, 0);
}

#define WAITK(nstr)                                          \
  asm volatile("s_waitcnt vmcnt(" nstr ")" ::: "memory");    \
  __builtin_amdgcn_s_barrier();                              \
  asm volatile("" ::: "memory");

// ---------------------------------------------------------------------------
// Weight precompute (bf16 transposes) + zero bcnt.
// ---------------------------------------------------------------------------
__global__ void tran_kernel(const float* __restrict__ Wk,
                            const float* __restrict__ Wpu,
                            const float* __restrict__ Wpi,
                            const float* __restrict__ Wl,
                            ush* __restrict__ wkT, ush* __restrict__ wpTu,
                            ush* __restrict__ wpTi, ush* __restrict__ wlT,
                            int* __restrict__ bcnt)
{
  int idx = blockIdx.x * 256 + threadIdx.x;
  if (idx < NBT) bcnt[idx] = 0;
  const float* src; ush* dst; int K, M, li;
  if (idx < 65536)       { src = Wk;  dst = wkT;  K = 256; M = 256; li = idx; }
  else if (idx < 98304)  { src = Wpu; dst = wpTu; K = 128; M = 256; li = idx - 65536; }
  else if (idx < 131072) { src = Wpi; dst = wpTi; K = 128; M = 256; li = idx - 98304; }
  else                   { src = Wl;  dst = wlT;  K = 256; M = 64;  li = idx - 131072; }
  int m = li / K, k = li % K;
  dst[li] = (ush)bfr(src[k * M + m]);
}

// ---------------------------------------------------------------------------
// Projection v4 + fused node scores — FULL v10 structure:
//  - 2 sides x 196 blocks, 256 rows/block, 16 row-tiles
//  - x tiles (16 x 512B rows, same byte geometry as v10's z tiles) staged
//    into double-buffered LDS via gll16 with XOR-swizzled source; counted
//    vmcnt(2) keeps next tile in flight
//  - all 4 waves share the staged tile; B (wpT) pinned resident (64 VGPR)
//  - v3's wave-local score epilogue (heads 2w, 2w+1)
// ---------------------------------------------------------------------------
__global__ __launch_bounds__(256, 2) void proj_kernel(
    const float* __restrict__ xu, const float* __restrict__ xi,
    const ush* __restrict__ wpTu, const ush* __restrict__ wpTi,
    const float* __restrict__ bu, const float* __restrict__ bi,
    const float* __restrict__ au0, const float* __restrict__ au1,
    const float* __restrict__ au2, const float* __restrict__ au3,
    const float* __restrict__ ai0, const float* __restrict__ ai1,
    const float* __restrict__ ai2, const float* __restrict__ ai3,
    ush* __restrict__ hu, ush* __restrict__ hi,
    float* __restrict__ su, float* __restrict__ si)
{
  __shared__ float Asf[2][16 * 128];   // 8 KB per buffer (16 rows x 512B)
  const int bid = blockIdx.x;
  const int side = bid >= PJQ;
  const float* x = side ? xi : xu;
  const ush* wpT = side ? wpTi : wpTu;
  const float* b = side ? bi : bu;
  ush* hb = side ? hi : hu;
  float* sdst = side ? si : su;
  const float* a0 = side ? ai0 : au0;
  const float* a1 = side ? ai1 : au1;
  const float* a2 = side ? ai2 : au2;
  const float* a3 = side ? ai3 : au3;
  const int t = threadIdx.x;
  const int w = t >> 6, l = t & 63;
  const int lrow = l & 15, kgrp = l >> 4;
  const int row0 = (bid - side * PJQ) * 256;

  // B fragments (wave's 4 nt-tiles): loaded once, pinned resident.
  u32 B[4][4][4];
  float bias[4], av[4][4];
#pragma unroll
  for (int j = 0; j < 4; ++j) {
    const int col = (w * 4 + j) * 16 + lrow;
    bias[j] = b[col];
    av[0][j] = a0[col]; av[1][j] = a1[col];
    av[2][j] = a2[col]; av[3][j] = a3[col];
#pragma unroll
    for (int ks = 0; ks < 4; ++ks) {
      uint4 v = *(const uint4*)&wpT[(size_t)col * F_IN + ks * 32 + kgrp * 8];
      B[j][ks][0] = v.x; B[j][ks][1] = v.y; B[j][ks][2] = v.z; B[j][ks][3] = v.w;
      asm volatile("" : "+v"(B[j][ks][0]), "+v"(B[j][ks][1]),
                        "+v"(B[j][ks][2]), "+v"(B[j][ks][3]));
    }
  }

  // stage 16-row x tile rt: 512 16B-chunks; chunk q16 -> row r=q16>>5,
  // data-chunk c=(q16&31)^(r&7) (pre-swizzled source; LDS dest linear).
  auto stage = [&](int buf, int rt) {
#pragma unroll
    for (int i = 0; i < 2; ++i) {
      int q16 = i * 256 + t;
      int r = q16 >> 5;
      int c = (q16 & 31) ^ (r & 7);
      int gr = row0 + rt * 16 + r;
      if (gr >= N) gr = N - 1;
      gll16(&x[(size_t)gr * F_IN + c * 4], &Asf[buf][(i * 256 + w * 64) * 4]);
    }
  };

  stage(0, 0);
  int cur = 0;
  for (int rt = 0; rt < 16; ++rt) {
    if (rt < 15) {
      stage(cur ^ 1, rt + 1);
      WAITK("2");
    } else {
      WAITK("0");
    }
    const int arow0 = row0 + rt * 16;
    // A-pack from LDS (swizzled chunks; fragment ks = chunks 2*(ks*4+kgrp), +1)
    bf16x8 Af[4];
#pragma unroll
    for (int ks = 0; ks < 4; ++ks) {
      const int c0 = (ks * 8 + kgrp * 2) ^ (lrow & 7);
      const int c1 = (ks * 8 + kgrp * 2 + 1) ^ (lrow & 7);
      f4 v0 = *(const f4*)&Asf[cur][lrow * 128 + c0 * 4];
      f4 v1 = *(const f4*)&Asf[cur][lrow * 128 + c1 * 4];
      union { u32 u[4]; bf16x8 v; } c;
      c.u[0] = pk2(v0.x, v0.y); c.u[1] = pk2(v0.z, v0.w);
      c.u[2] = pk2(v1.x, v1.y); c.u[3] = pk2(v1.z, v1.w);
      Af[ks] = c.v;
    }
    f32x4 acc[4];
    const f32x4 zz = {0.f, 0.f, 0.f, 0.f};
#pragma unroll
    for (int j = 0; j < 4; ++j) acc[j] = zz;
#pragma unroll
    for (int ks = 0; ks < 4; ++ks)
#pragma unroll
      for (int j = 0; j < 4; ++j) {
        union { u32 u[4]; bf16x8 v; } bb;
        bb.u[0] = B[j][ks][0]; bb.u[1] = B[j][ks][1];
        bb.u[2] = B[j][ks][2]; bb.u[3] = B[j][ks][3];
        acc[j] = __builtin_amdgcn_mfma_f32_16x16x32_bf16(Af[ks], bb.v, acc[j], 0, 0, 0);
      }

    // epilogue: h write + node scores (heads 2w, 2w+1 wave-local)
    float pk_[4][4];
#pragma unroll
    for (int j = 0; j < 4; ++j) {
      if ((j & 1) == 0) {
#pragma unroll
        for (int k = 0; k < 4; ++k)
#pragma unroll
          for (int i = 0; i < 4; ++i) pk_[k][i] = 0.f;
      }
      const int col = (w * 4 + j) * 16 + lrow;
#pragma unroll
      for (int i = 0; i < 4; ++i) {
        float hv = acc[j][i] + bias[j];
        int gr = arow0 + kgrp * 4 + i;
        if (gr < N) hb[(size_t)gr * HID + col] = (ush)bfr(hv);
        pk_[0][i] = fmaf(hv, av[0][j], pk_[0][i]);
        pk_[1][i] = fmaf(hv, av[1][j], pk_[1][i]);
        pk_[2][i] = fmaf(hv, av[2][j], pk_[2][i]);
        pk_[3][i] = fmaf(hv, av[3][j], pk_[3][i]);
      }
      if (j & 1) {
        const int head = 2 * w + (j >> 1);
#pragma unroll
        for (int k = 0; k < 4; ++k)
#pragma unroll
          for (int i = 0; i < 4; ++i) {
            float p = pk_[k][i];
            p += __shfl_xor(p, 1);
            p += __shfl_xor(p, 2);
            p += __shfl_xor(p, 4);
            p += __shfl_xor(p, 8);
            int gr = arow0 + kgrp * 4 + i;
            if (lrow == 0 && gr < N)
              sdst[(size_t)k * N8 + (size_t)gr * 8 + head] = p;
          }
      }
    }
    __syncthreads();   // all waves done reading Asf[cur] before next overwrite
    cur ^= 1;
  }
}

// ---------------------------------------------------------------------------
// scat2 single-pass (R14, unchanged).
// ---------------------------------------------------------------------------
__global__ __launch_bounds__(256) void scat2_kernel(
    const int* __restrict__ s0, const int* __restrict__ d0,
    const int* __restrict__ s1, const int* __restrict__ d1,
    const int* __restrict__ s2, const int* __restrict__ d2,
    const int* __restrict__ s3, const int* __restrict__ d3,
    int* __restrict__ bcnt, u32* __restrict__ bstage)
{
  __shared__ int lh[NBUK];
  const int rel = blockIdx.x / NB1;
  const int blk = blockIdx.x % NB1;
  const int* sp = rel == 0 ? s0 : rel == 1 ? s1 : rel == 2 ? s2 : s3;
  const int* dp = rel == 0 ? d0 : rel == 1 ? d1 : rel == 2 ? d2 : d3;
  for (int j = threadIdx.x; j < NBUK; j += 256) lh[j] = 0;
  __syncthreads();
  const int base = blk * EPB1;
  int sr[32], dr[32];
#pragma unroll
  for (int k = 0; k < 32; ++k) {
    int i = base + k * 256 + threadIdx.x;
    sr[k] = (i < E) ? sp[i] : -1;
    dr[k] = (i < E) ? dp[i] : -1;
  }
#pragma unroll
  for (int k = 0; k < 32; ++k)
    if (dr[k] >= 0) atomicAdd(&lh[dr[k] >> BSH], 1);
  __syncthreads();
  for (int j = threadIdx.x; j < NBUK; j += 256) {
    int c = lh[j];
    int gb = rel * NBUK + j;
    lh[j] = c ? gb * BCAP + atomicAdd(&bcnt[gb], c) : 0;
  }
  __syncthreads();
#pragma unroll
  for (int k = 0; k < 32; ++k)
    if (dr[k] >= 0) {
      int pos = atomicAdd(&lh[dr[k] >> BSH], 1);
      bstage[pos] = ((u32)dr[k] << 16) | (u32)sr[k];
    }
}

// ---------------------------------------------------------------------------
// Fused fillb (R13, unchanged).
// ---------------------------------------------------------------------------
__global__ __launch_bounds__(256) void fillb_kernel(
    const u32* __restrict__ bstage, const int* __restrict__ bcnt,
    int* __restrict__ start, int* __restrict__ count, int* __restrict__ csr)
{
  __shared__ int lcnt[128];
  __shared__ int lpos[128];
  const int bb = blockIdx.x;
  const int rel = bb / NBUK, b = bb % NBUK;
  const int base = bb * BCAP;
  const int cnt = bcnt[bb];
  const int t = threadIdx.x;
  if (t < 128) lcnt[t] = 0;
  __syncthreads();
  for (int k = t; k < cnt; k += 256)
    atomicAdd(&lcnt[(bstage[base + k] >> 16) & 127], 1);
  __syncthreads();
  if (t < 128) lpos[t] = lcnt[t];
  __syncthreads();
  for (int off = 1; off < 128; off <<= 1) {
    int v = (t < 128 && t >= off) ? lpos[t - off] : 0;
    __syncthreads();
    if (t < 128) lpos[t] += v;
    __syncthreads();
  }
  const int fb = rel * N + b * 128;
  const int lim = min(128, N - b * 128);
  if (t < 128) {
    int ex = base + lpos[t] - lcnt[t];
    if (t < lim) {
      start[fb + t] = ex;
      count[fb + t] = lcnt[t];
    }
    lcnt[t] = ex;
  }
  __syncthreads();
  for (int k = t; k < cnt; k += 256) {
    u32 pk = bstage[base + k];
    int pos = atomicAdd(&lcnt[(pk >> 16) & 127], 1);
    csr[pos] = (int)(pk & 0xffffu);
  }
}

// ---------------------------------------------------------------------------
// Relation conv (R11 single-pass, 8-edge batches), 4 dispatches.
// ---------------------------------------------------------------------------
#define CONV_EDGE(sx)                                                     \
  {                                                                       \
    float al = __expf(lrelu(lg##sx + sdv2));                              \
    den += al;                                                            \
    a0 = fmaf(al, bf2f(v##sx.x), a0); a1 = fmaf(al, bf2f(v##sx.y), a1);   \
    a2 = fmaf(al, bf2f(v##sx.z), a2); a3 = fmaf(al, bf2f(v##sx.w), a3);   \
  }

__global__ __launch_bounds__(256) void conv_kernel(
    int rel,
    const ush* __restrict__ hub, const ush* __restrict__ hib,
    const float* __restrict__ su, const float* __restrict__ si,
    const int* __restrict__ csr,
    const int* __restrict__ start, const int* __restrict__ count,
    ush* __restrict__ zall)
{
  const int dst = blockIdx.x * 4 + (threadIdx.x >> 6);
  const int lane = threadIdx.x & 63;
  const ush* xsb = (rel == 0 || rel == 3) ? hib : hub;
  const float* ss = rel == 0 ? si : rel == 1 ? su + N8 :
                    rel == 2 ? su + 3 * (size_t)N8 : si + 2 * (size_t)N8;
  const float* sd = rel == 0 ? su : rel == 1 ? su + 2 * (size_t)N8 :
                    rel == 2 ? si + N8 : si + 3 * (size_t)N8;
  const int grow = rel * N + dst;
  const int e0 = start[grow];
  const int ne = count[grow];

  const int h2 = lane >> 3;
  const float sdv2 = sd[dst * 8 + h2];

  float den = 0.f;
  float a0 = 0.f, a1 = 0.f, a2 = 0.f, a3 = 0.f;
  int j = 0;
  for (; j + 8 <= ne; j += 8) {
    int s0_ = csr[e0 + j + 0], s1_ = csr[e0 + j + 1];
    int s2_ = csr[e0 + j + 2], s3_ = csr[e0 + j + 3];
    int s4_ = csr[e0 + j + 4], s5_ = csr[e0 + j + 5];
    int s6_ = csr[e0 + j + 6], s7_ = csr[e0 + j + 7];
    float lg0 = ss[s0_ * 8 + h2], lg1 = ss[s1_ * 8 + h2];
    float lg2 = ss[s2_ * 8 + h2], lg3 = ss[s3_ * 8 + h2];
    float lg4 = ss[s4_ * 8 + h2], lg5 = ss[s5_ * 8 + h2];
    float lg6 = ss[s6_ * 8 + h2], lg7 = ss[s7_ * 8 + h2];
    ushort4 v0 = *(const ushort4*)&xsb[(size_t)s0_ * HID + lane * 4];
    ushort4 v1 = *(const ushort4*)&xsb[(size_t)s1_ * HID + lane * 4];
    ushort4 v2 = *(const ushort4*)&xsb[(size_t)s2_ * HID + lane * 4];
    ushort4 v3 = *(const ushort4*)&xsb[(size_t)s3_ * HID + lane * 4];
    ushort4 v4 = *(const ushort4*)&xsb[(size_t)s4_ * HID + lane * 4];
    ushort4 v5 = *(const ushort4*)&xsb[(size_t)s5_ * HID + lane * 4];
    ushort4 v6 = *(const ushort4*)&xsb[(size_t)s6_ * HID + lane * 4];
    ushort4 v7 = *(const ushort4*)&xsb[(size_t)s7_ * HID + lane * 4];
    CONV_EDGE(0) CONV_EDGE(1) CONV_EDGE(2) CONV_EDGE(3)
    CONV_EDGE(4) CONV_EDGE(5) CONV_EDGE(6) CONV_EDGE(7)
  }
  for (; j + 2 <= ne; j += 2) {
    int s0_ = csr[e0 + j + 0], s1_ = csr[e0 + j + 1];
    float lg0 = ss[s0_ * 8 + h2], lg1 = ss[s1_ * 8 + h2];
    ushort4 v0 = *(const ushort4*)&xsb[(size_t)s0_ * HID + lane * 4];
    ushort4 v1 = *(const ushort4*)&xsb[(size_t)s1_ * HID + lane * 4];
    CONV_EDGE(0) CONV_EDGE(1)
  }
  if (j < ne) {
    int s0_ = csr[e0 + j];
    float lg0 = ss[s0_ * 8 + h2];
    ushort4 v0 = *(const ushort4*)&xsb[(size_t)s0_ * HID + lane * 4];
    CONV_EDGE(0)
  }
  const float inv = 1.f / (den + 1e-16f);
  ushort4 o;
  o.x = (ush)bfr(fmaxf(a0 * inv, 0.f));
  o.y = (ush)bfr(fmaxf(a1 * inv, 0.f));
  o.z = (ush)bfr(fmaxf(a2 * inv, 0.f));
  o.w = (ush)bfr(fmaxf(a3 * inv, 0.f));
  *(ushort4*)&zall[(size_t)grow * HID + lane * 4] = o;
}

// ---------------------------------------------------------------------------
// Semantic scores v10 (R19, unchanged — B-resident, A via shared LDS).
// ---------------------------------------------------------------------------
__global__ __launch_bounds__(256, 2) void semscore_kernel(
    const ush* __restrict__ zall, const ush* __restrict__ wkT,
    const float* __restrict__ bk, const float* __restrict__ q,
    float* __restrict__ parts)
{
  __shared__ ush As[2][16 * 256];
  __shared__ float red[4];
  const int bid = blockIdx.x;
  const int mat = bid / SMQ;
  const int rb  = bid % SMQ;
  const ush* zsrc = zall + (size_t)mat * N * HID;
  const int t = threadIdx.x;
  const int w = t >> 6, l = t & 63;
  const int lrow = l & 15, kgrp = l >> 4;
  const int row0 = rb * 512;

  u32 B[4][8][4];
  float bkv[4], qv[4];
#pragma unroll
  for (int j = 0; j < 4; ++j) {
    const int col = (w * 4 + j) * 16 + lrow;
    bkv[j] = bk[col];
    qv[j] = q[col];
#pragma unroll
    for (int ks = 0; ks < 8; ++ks) {
      uint4 v = *(const uint4*)&wkT[(size_t)col * HID + ks * 32 + kgrp * 8];
      B[j][ks][0] = v.x; B[j][ks][1] = v.y; B[j][ks][2] = v.z; B[j][ks][3] = v.w;
      asm volatile("" : "+v"(B[j][ks][0]), "+v"(B[j][ks][1]),
                        "+v"(B[j][ks][2]), "+v"(B[j][ks][3]));
    }
  }

  auto stage = [&](int buf, int rt) {
#pragma unroll
    for (int i = 0; i < 2; ++i) {
      int q16 = i * 256 + t;
      int r = q16 >> 5;
      int c = (q16 & 31) ^ (r & 7);
      int gr = row0 + rt * 16 + r;
      if (gr >= N) gr = N - 1;
      gll16(&zsrc[(size_t)gr * HID + c * 8], &As[buf][(i * 256 + w * 64) * 8]);
    }
  };

  float s = 0.f;
  stage(0, 0);
  int cur = 0;
  for (int rt = 0; rt < 32; ++rt) {
    if (rt < 31) {
      stage(cur ^ 1, rt + 1);
      WAITK("2");
    } else {
      WAITK("0");
    }
    f32x4 acc[4];
    const f32x4 zz = {0.f, 0.f, 0.f, 0.f};
#pragma unroll
    for (int j = 0; j < 4; ++j) acc[j] = zz;
#pragma unroll
    for (int ks = 0; ks < 8; ++ks) {
      const int ch = (ks * 4 + kgrp) ^ (lrow & 7);
      bf16x8 Af = *(const bf16x8*)&As[cur][(lrow * 32 + ch) * 8];
#pragma unroll
      for (int j = 0; j < 4; ++j) {
        union { u32 u[4]; bf16x8 v; } bb;
        bb.u[0] = B[j][ks][0]; bb.u[1] = B[j][ks][1];
        bb.u[2] = B[j][ks][2]; bb.u[3] = B[j][ks][3];
        acc[j] = __builtin_amdgcn_mfma_f32_16x16x32_bf16(Af, bb.v, acc[j], 0, 0, 0);
      }
    }
#pragma unroll
    for (int j = 0; j < 4; ++j)
#pragma unroll
      for (int i = 0; i < 4; ++i) {
        int gr = row0 + rt * 16 + kgrp * 4 + i;
        if (gr < N) s += tanh_fast(acc[j][i] + bkv[j]) * qv[j];
      }
    __syncthreads();
    cur ^= 1;
  }

#pragma unroll
  for (int off = 1; off < 64; off <<= 1) s += __shfl_xor(s, off);
  if (l == 0) red[w] = s;
  __syncthreads();
  if (t == 0) parts[bid] = red[0] + red[1] + red[2] + red[3];
}

// ---------------------------------------------------------------------------
// Final v3 (R20, unchanged — B pinned, partial-reduce + softmax inline).
// ---------------------------------------------------------------------------
__global__ __launch_bounds__(256, 2) void final_kernel(
    const ush* __restrict__ zbu0, const ush* __restrict__ zbu1,
    const ush* __restrict__ zbi0, const ush* __restrict__ zbi1,
    const float* __restrict__ parts, const ush* __restrict__ wlT,
    const float* __restrict__ bl, float* __restrict__ out)
{
  __shared__ float redA[4], redB[4], attn[2];
  const int bid = blockIdx.x;
  const int side = bid >= FB;
  const ush* z0 = side ? zbi0 : zbu0;
  const ush* z1 = side ? zbi1 : zbu1;
  float* op = out + (size_t)side * N * OUTD;
  const int t = threadIdx.x;
  const int w = t >> 6, l = t & 63;
  const int lrow = l & 15, kgrp = l >> 4;

  u32 B[4][8][4];
  float blv[4];
#pragma unroll
  for (int nt = 0; nt < 4; ++nt) {
    const int col = nt * 16 + lrow;
    blv[nt] = bl[col];
#pragma unroll
    for (int ks = 0; ks < 8; ++ks) {
      uint4 v = *(const uint4*)&wlT[(size_t)col * HID + ks * 32 + kgrp * 8];
      B[nt][ks][0] = v.x; B[nt][ks][1] = v.y; B[nt][ks][2] = v.z; B[nt][ks][3] = v.w;
      asm volatile("" : "+v"(B[nt][ks][0]), "+v"(B[nt][ks][1]),
                        "+v"(B[nt][ks][2]), "+v"(B[nt][ks][3]));
    }
  }

  const float* p0 = parts + (size_t)(side * 2) * SMQ;
  const float* p1 = p0 + SMQ;
  float s0 = 0.f, s1 = 0.f;
  for (int i = t; i < SMQ; i += 256) { s0 += p0[i]; s1 += p1[i]; }
#pragma unroll
  for (int off = 1; off < 64; off <<= 1) {
    s0 += __shfl_xor(s0, off);
    s1 += __shfl_xor(s1, off);
  }
  if (l == 0) { redA[w] = s0; redB[w] = s1; }
  __syncthreads();
  if (t == 0) {
    const float inv_n = 1.f / (float)N;
    float r0 = (redA[0] + redA[1] + redA[2] + redA[3]) * inv_n;
    float r1 = (redB[0] + redB[1] + redB[2] + redB[3]) * inv_n;
    float mm = fmaxf(r0, r1);
    float e0 = __expf(r0 - mm), e1 = __expf(r1 - mm);
    attn[0] = e0 / (e0 + e1);
    attn[1] = e1 / (e0 + e1);
  }
  __syncthreads();
  const float a0 = attn[0], a1 = attn[1];

  const int base = (bid - side * FB) * 64;
  int arow = base + w * 16 + lrow;
  if (arow >= N) arow = N - 1;

  bf16x8 Af[8];
#pragma unroll
  for (int ks = 0; ks < 8; ++ks) {
    const ush* pz0 = &z0[(size_t)arow * HID + ks * 32 + kgrp * 8];
    const ush* pz1 = &z1[(size_t)arow * HID + ks * 32 + kgrp * 8];
    ushort4 u0a = *(const ushort4*)pz0, u0b = *(const ushort4*)(pz0 + 4);
    ushort4 u1a = *(const ushort4*)pz1, u1b = *(const ushort4*)(pz1 + 4);
    union { u32 u[4]; bf16x8 v; } c;
    c.u[0] = pk2(a0 * bf2f(u0a.x) + a1 * bf2f(u1a.x),
                 a0 * bf2f(u0a.y) + a1 * bf2f(u1a.y));
    c.u[1] = pk2(a0 * bf2f(u0a.z) + a1 * bf2f(u1a.z),
                 a0 * bf2f(u0a.w) + a1 * bf2f(u1a.w));
    c.u[2] = pk2(a0 * bf2f(u0b.x) + a1 * bf2f(u1b.x),
                 a0 * bf2f(u0b.y) + a1 * bf2f(u1b.y));
    c.u[3] = pk2(a0 * bf2f(u0b.z) + a1 * bf2f(u1b.z),
                 a0 * bf2f(u0b.w) + a1 * bf2f(u1b.w));
    Af[ks] = c.v;
  }

#pragma unroll
  for (int nt = 0; nt < 4; ++nt) {
    const int col = nt * 16 + lrow;
    f32x4 acc = {0.f, 0.f, 0.f, 0.f};
#pragma unroll
    for (int ks = 0; ks < 8; ++ks) {
      union { u32 u[4]; bf16x8 v; } bb;
      bb.u[0] = B[nt][ks][0]; bb.u[1] = B[nt][ks][1];
      bb.u[2] = B[nt][ks][2]; bb.u[3] = B[nt][ks][3];
      acc = __builtin_amdgcn_mfma_f32_16x16x32_bf16(Af[ks], bb.v, acc, 0, 0, 0);
    }
    const float bb = blv[nt];
#pragma unroll
    for (int i = 0; i < 4; ++i) {
      int gr = base + w * 16 + kgrp * 4 + i;
      if (gr < N) op[(size_t)gr * OUTD + col] = acc[i] + bb;
    }
  }
}

// ---------------------------------------------------------------------------
extern "C" void kernel_launch(void* const* d_in, const int* in_sizes, int n_in,
                              void* d_out, int out_size, void* d_ws, size_t ws_size,
                              hipStream_t stream)
{
  const float* x_user = (const float*)d_in[0];
  const float* x_item = (const float*)d_in[1];
  const int*   e_ui   = (const int*)d_in[2];
  const int*   e_iu   = (const int*)d_in[3];
  const int*   e_uu   = (const int*)d_in[4];
  const int*   e_ii   = (const int*)d_in[5];
  const float* Wp_u   = (const float*)d_in[6];
  const float* bp_u   = (const float*)d_in[7];
  const float* Wp_i   = (const float*)d_in[8];
  const float* bp_i   = (const float*)d_in[9];
  const float* as_ui  = (const float*)d_in[10];
  const float* ad_ui  = (const float*)d_in[11];
  const float* as_iu  = (const float*)d_in[12];
  const float* ad_iu  = (const float*)d_in[13];
  const float* as_uu  = (const float*)d_in[14];
  const float* ad_uu  = (const float*)d_in[15];
  const float* as_ii  = (const float*)d_in[16];
  const float* ad_ii  = (const float*)d_in[17];
  const float* Wk     = (const float*)d_in[18];
  const float* bk     = (const float*)d_in[19];
  const float* q      = (const float*)d_in[20];
  const float* Wl     = (const float*)d_in[21];
  const float* bl     = (const float*)d_in[22];

  const size_t NH = (size_t)N * HID;
  const size_t WT = 65536 + 2 * 32768 + 16384;
  size_t need = (8 * (size_t)N8 + 4 * (size_t)SMQ + 4) * 4
              + (6 * NH + WT) * 2
              + ((size_t)8 * N + (size_t)NBT * BCAP + NBT) * 4;
  if (ws_size < need) {
    hipMemsetAsync(d_out, 0x7f, (size_t)out_size * sizeof(float), stream);
    return;
  }
  float* su = (float*)d_ws;
  float* si = su + 4 * (size_t)N8;
  float* parts = si + 4 * (size_t)N8;
  ush* zbu0 = (ush*)(parts + 4 * (size_t)SMQ + 4);
  ush* zbu1 = zbu0 + NH;
  ush* zbi0 = zbu1 + NH;
  ush* zbi1 = zbi0 + NH;
  ush* hub  = zbi1 + NH;
  ush* hib  = hub + NH;
  ush* wkT  = hib + NH;
  ush* wpTu = wkT + 65536;
  ush* wpTi = wpTu + 32768;
  ush* wlT  = wpTi + 32768;
  int* count  = (int*)(wlT + 16384);
  int* start  = count + NTOT;
  int* bcnt   = start + NTOT;
  int* csr    = bcnt + NBT;
  u32* bstage = (u32*)zbu0;     // 16.0 MB <= 25.6 MB (dead until conv)

  // 1. weight transposes + zero bcnt
  tran_kernel<<<576, 256, 0, stream>>>(Wk, Wp_u, Wp_i, Wl, wkT, wpTu, wpTi, wlT,
                                       bcnt);
  // 2. projections + fused node scores (full v10 structure)
  proj_kernel<<<2 * PJQ, 256, 0, stream>>>(x_user, x_item, wpTu, wpTi, bp_u, bp_i,
                                           ad_iu, as_uu, ad_uu, as_ui,
                                           as_iu, ad_ui, as_ii, ad_ii,
                                           hub, hib, su, si);
  // 3. multisplit into fixed-capacity buckets (single edge pass)
  scat2_kernel<<<4 * NB1, 256, 0, stream>>>(e_iu, e_iu + E, e_uu, e_uu + E,
                                            e_ui, e_ui + E, e_ii, e_ii + E,
                                            bcnt, bstage);
  // 4. fused fine count + scan + csr fill
  fillb_kernel<<<NBT, 256, 0, stream>>>(bstage, bcnt, start, count, csr);
  // 5. relation convs — 4 dispatches (counter visibility)
  for (int rel = 0; rel < 4; ++rel)
    conv_kernel<<<N / 4, 256, 0, stream>>>(rel, hub, hib, su, si, csr, start,
                                           count, zbu0);
  // 6. semantic attention partials (B-resident, A via shared LDS)
  semscore_kernel<<<4 * SMQ, 256, 0, stream>>>(zbu0, wkT, bk, q, parts);
  // 7. final linear (B-resident, partial-reduce + softmax inline)
  final_kernel<<<2 * FB, 256, 0, stream>>>(zbu0, zbu1, zbi0, zbi1, parts, wlT, bl,
                                           (float*)d_out);
}

// Round 22
// 538.510 us; speedup vs baseline: 1.0560x; 1.0560x over previous
//
#include <hip/hip_runtime.h>
#include <math.h>

#define N     50000
#define F_IN  128
#define HID   256
#define E     800000
#define OUTD  64
#define NEG   0.2f
#define N8    (N * 8)
#define NTOT  (4 * N)
#define FB    ((N + 63) / 64)        // 782 64-row blocks (proj/final)
#define SMQ   98                     // semscore row-blocks per matrix (98*512 >= N)

// bucket sort geometry (fixed-capacity buckets)
#define BSH   7
#define NBUK  ((N + 127) / 128)      // 391
#define NBT   (4 * NBUK)             // 1564
#define BCAP  2560                   // Poisson(2048) + 11 sigma headroom
#define EPB1  8192
#define NB1   ((E + EPB1 - 1) / EPB1) // 98

typedef float4 f4;
typedef unsigned int u32;
typedef unsigned short ush;
typedef float f32x4 __attribute__((ext_vector_type(4)));
typedef short bf16x8 __attribute__((ext_vector_type(8)));

static __device__ __forceinline__ float lrelu(float x) { return x >= 0.f ? x : NEG * x; }
static __device__ __forceinline__ u32 bfr(float x) {
  u32 u = __float_as_uint(x);
  return (u + 0x7fffu + ((u >> 16) & 1u)) >> 16;
}
static __device__ __forceinline__ u32 pk2(float a, float b) { return bfr(a) | (bfr(b) << 16); }
static __device__ __forceinline__ float bf2f(u32 us) { return __uint_as_float(us << 16); }
static __device__ __forceinline__ float tanh_fast(float x) {
  float e = __expf(2.f * x);
  return fmaf(-2.f, __builtin_amdgcn_rcpf(e + 1.f), 1.f);
}

typedef const __attribute__((address_space(1))) unsigned int gu32;
typedef __attribute__((address_space(3))) unsigned int lu32;
static __device__ __forceinline__ void gll16(const void* g, void* l) {
  __builtin_amdgcn_global_load_lds((gu32*)g, (lu32*)l, 16, 0, 0);
}

#define WAITK(nstr)                                          \
  asm volatile("s_waitcnt vmcnt(" nstr ")" ::: "memory");    \
  __builtin_amdgcn_s_barrier();                              \
  asm volatile("" ::: "memory");

// ---------------------------------------------------------------------------
// Weight precompute (bf16 transposes) + zero bcnt.
// ---------------------------------------------------------------------------
__global__ void tran_kernel(const float* __restrict__ Wk,
                            const float* __restrict__ Wpu,
                            const float* __restrict__ Wpi,
                            const float* __restrict__ Wl,
                            ush* __restrict__ wkT, ush* __restrict__ wpTu,
                            ush* __restrict__ wpTi, ush* __restrict__ wlT,
                            int* __restrict__ bcnt)
{
  int idx = blockIdx.x * 256 + threadIdx.x;
  if (idx < NBT) bcnt[idx] = 0;
  const float* src; ush* dst; int K, M, li;
  if (idx < 65536)       { src = Wk;  dst = wkT;  K = 256; M = 256; li = idx; }
  else if (idx < 98304)  { src = Wpu; dst = wpTu; K = 128; M = 256; li = idx - 65536; }
  else if (idx < 131072) { src = Wpi; dst = wpTi; K = 128; M = 256; li = idx - 98304; }
  else                   { src = Wl;  dst = wlT;  K = 256; M = 64;  li = idx - 131072; }
  int m = li / K, k = li % K;
  dst[li] = (ush)bfr(src[k * M + m]);
}

// ---------------------------------------------------------------------------
// Projection + FUSED node scores (R14/R19 version — best measured).
// ---------------------------------------------------------------------------
__global__ __launch_bounds__(256) void proj_kernel(
    const float* __restrict__ xu, const float* __restrict__ xi,
    const ush* __restrict__ wpTu, const ush* __restrict__ wpTi,
    const float* __restrict__ bu, const float* __restrict__ bi,
    const float* __restrict__ au0, const float* __restrict__ au1,
    const float* __restrict__ au2, const float* __restrict__ au3,
    const float* __restrict__ ai0, const float* __restrict__ ai1,
    const float* __restrict__ ai2, const float* __restrict__ ai3,
    ush* __restrict__ hu, ush* __restrict__ hi,
    float* __restrict__ su, float* __restrict__ si)
{
  const int bid = blockIdx.x;
  const int side = bid >= FB;
  const float* x = side ? xi : xu;
  const ush* wpT = side ? wpTi : wpTu;
  const float* b = side ? bi : bu;
  ush* hb = side ? hi : hu;
  float* sdst = side ? si : su;
  const float* a0 = side ? ai0 : au0;
  const float* a1 = side ? ai1 : au1;
  const float* a2 = side ? ai2 : au2;
  const float* a3 = side ? ai3 : au3;
  const int t = threadIdx.x;
  const int w = t >> 6, l = t & 63;
  const int lrow = l & 15, kgrp = l >> 4;
  const int base = (bid - side * FB) * 64;
  int arow = base + w * 16 + lrow;
  if (arow >= N) arow = N - 1;

  bf16x8 Af[4];
#pragma unroll
  for (int ks = 0; ks < 4; ++ks) {
    const float* px = &x[(size_t)arow * F_IN + ks * 32 + kgrp * 8];
    f4 v0 = *(const f4*)px;
    f4 v1 = *(const f4*)(px + 4);
    union { u32 u[4]; bf16x8 v; } c;
    c.u[0] = pk2(v0.x, v0.y); c.u[1] = pk2(v0.z, v0.w);
    c.u[2] = pk2(v1.x, v1.y); c.u[3] = pk2(v1.z, v1.w);
    Af[ks] = c.v;
  }

  float pk_[4][4] = {};
#pragma unroll
  for (int nt = 0; nt < 16; ++nt) {
    const int col = nt * 16 + lrow;
    f32x4 acc = {0.f, 0.f, 0.f, 0.f};
#pragma unroll
    for (int ks = 0; ks < 4; ++ks) {
      bf16x8 Bf = *(const bf16x8*)&wpT[(size_t)col * F_IN + ks * 32 + kgrp * 8];
      acc = __builtin_amdgcn_mfma_f32_16x16x32_bf16(Af[ks], Bf, acc, 0, 0, 0);
    }
    const float bb = b[col];
    const float av0 = a0[col], av1 = a1[col], av2 = a2[col], av3 = a3[col];
#pragma unroll
    for (int i = 0; i < 4; ++i) {
      float hv = acc[i] + bb;
      int gr = base + w * 16 + kgrp * 4 + i;
      if (gr < N) hb[(size_t)gr * HID + col] = (ush)bfr(hv);
      pk_[0][i] = fmaf(hv, av0, pk_[0][i]);
      pk_[1][i] = fmaf(hv, av1, pk_[1][i]);
      pk_[2][i] = fmaf(hv, av2, pk_[2][i]);
      pk_[3][i] = fmaf(hv, av3, pk_[3][i]);
    }
    if (nt & 1) {
      const int head = nt >> 1;
#pragma unroll
      for (int k = 0; k < 4; ++k)
#pragma unroll
        for (int i = 0; i < 4; ++i) {
          float p = pk_[k][i];
          p += __shfl_xor(p, 1);
          p += __shfl_xor(p, 2);
          p += __shfl_xor(p, 4);
          p += __shfl_xor(p, 8);
          int gr = base + w * 16 + kgrp * 4 + i;
          if (lrow == 0 && gr < N)
            sdst[(size_t)k * N8 + (size_t)gr * 8 + head] = p;
          pk_[k][i] = 0.f;
        }
    }
  }
}

// ---------------------------------------------------------------------------
// scat2 single-pass (R14, unchanged).
// ---------------------------------------------------------------------------
__global__ __launch_bounds__(256) void scat2_kernel(
    const int* __restrict__ s0, const int* __restrict__ d0,
    const int* __restrict__ s1, const int* __restrict__ d1,
    const int* __restrict__ s2, const int* __restrict__ d2,
    const int* __restrict__ s3, const int* __restrict__ d3,
    int* __restrict__ bcnt, u32* __restrict__ bstage)
{
  __shared__ int lh[NBUK];
  const int rel = blockIdx.x / NB1;
  const int blk = blockIdx.x % NB1;
  const int* sp = rel == 0 ? s0 : rel == 1 ? s1 : rel == 2 ? s2 : s3;
  const int* dp = rel == 0 ? d0 : rel == 1 ? d1 : rel == 2 ? d2 : d3;
  for (int j = threadIdx.x; j < NBUK; j += 256) lh[j] = 0;
  __syncthreads();
  const int base = blk * EPB1;
  int sr[32], dr[32];
#pragma unroll
  for (int k = 0; k < 32; ++k) {
    int i = base + k * 256 + threadIdx.x;
    sr[k] = (i < E) ? sp[i] : -1;
    dr[k] = (i < E) ? dp[i] : -1;
  }
#pragma unroll
  for (int k = 0; k < 32; ++k)
    if (dr[k] >= 0) atomicAdd(&lh[dr[k] >> BSH], 1);
  __syncthreads();
  for (int j = threadIdx.x; j < NBUK; j += 256) {
    int c = lh[j];
    int gb = rel * NBUK + j;
    lh[j] = c ? gb * BCAP + atomicAdd(&bcnt[gb], c) : 0;
  }
  __syncthreads();
#pragma unroll
  for (int k = 0; k < 32; ++k)
    if (dr[k] >= 0) {
      int pos = atomicAdd(&lh[dr[k] >> BSH], 1);
      bstage[pos] = ((u32)dr[k] << 16) | (u32)sr[k];
    }
}

// ---------------------------------------------------------------------------
// Fused fillb (R13, unchanged).
// ---------------------------------------------------------------------------
__global__ __launch_bounds__(256) void fillb_kernel(
    const u32* __restrict__ bstage, const int* __restrict__ bcnt,
    int* __restrict__ start, int* __restrict__ count, int* __restrict__ csr)
{
  __shared__ int lcnt[128];
  __shared__ int lpos[128];
  const int bb = blockIdx.x;
  const int rel = bb / NBUK, b = bb % NBUK;
  const int base = bb * BCAP;
  const int cnt = bcnt[bb];
  const int t = threadIdx.x;
  if (t < 128) lcnt[t] = 0;
  __syncthreads();
  for (int k = t; k < cnt; k += 256)
    atomicAdd(&lcnt[(bstage[base + k] >> 16) & 127], 1);
  __syncthreads();
  if (t < 128) lpos[t] = lcnt[t];
  __syncthreads();
  for (int off = 1; off < 128; off <<= 1) {
    int v = (t < 128 && t >= off) ? lpos[t - off] : 0;
    __syncthreads();
    if (t < 128) lpos[t] += v;
    __syncthreads();
  }
  const int fb = rel * N + b * 128;
  const int lim = min(128, N - b * 128);
  if (t < 128) {
    int ex = base + lpos[t] - lcnt[t];
    if (t < lim) {
      start[fb + t] = ex;
      count[fb + t] = lcnt[t];
    }
    lcnt[t] = ex;
  }
  __syncthreads();
  for (int k = t; k < cnt; k += 256) {
    u32 pk = bstage[base + k];
    int pos = atomicAdd(&lcnt[(pk >> 16) & 127], 1);
    csr[pos] = (int)(pk & 0xffffu);
  }
}

// ---------------------------------------------------------------------------
// Relation conv (R11 single-pass, 8-edge batches), MERGED back to ONE
// dispatch (R17/R18 A/B measured ~15us of inter-dispatch drain tails for
// the 4-way split; per-kernel counters no longer needed).
// ---------------------------------------------------------------------------
#define CONV_EDGE(sx)                                                     \
  {                                                                       \
    float al = __expf(lrelu(lg##sx + sdv2));                              \
    den += al;                                                            \
    a0 = fmaf(al, bf2f(v##sx.x), a0); a1 = fmaf(al, bf2f(v##sx.y), a1);   \
    a2 = fmaf(al, bf2f(v##sx.z), a2); a3 = fmaf(al, bf2f(v##sx.w), a3);   \
  }

__global__ __launch_bounds__(256) void conv_kernel(
    const ush* __restrict__ hub, const ush* __restrict__ hib,
    const float* __restrict__ su, const float* __restrict__ si,
    const int* __restrict__ csr,
    const int* __restrict__ start, const int* __restrict__ count,
    ush* __restrict__ zall)
{
  const int rel = blockIdx.x / (N / 4);
  const int lb  = blockIdx.x % (N / 4);
  const int dst = lb * 4 + (threadIdx.x >> 6);
  const int lane = threadIdx.x & 63;
  const ush* xsb = (rel == 0 || rel == 3) ? hib : hub;
  const float* ss = rel == 0 ? si : rel == 1 ? su + N8 :
                    rel == 2 ? su + 3 * (size_t)N8 : si + 2 * (size_t)N8;
  const float* sd = rel == 0 ? su : rel == 1 ? su + 2 * (size_t)N8 :
                    rel == 2 ? si + N8 : si + 3 * (size_t)N8;
  const int grow = rel * N + dst;
  const int e0 = start[grow];
  const int ne = count[grow];

  const int h2 = lane >> 3;
  const float sdv2 = sd[dst * 8 + h2];

  float den = 0.f;
  float a0 = 0.f, a1 = 0.f, a2 = 0.f, a3 = 0.f;
  int j = 0;
  for (; j + 8 <= ne; j += 8) {
    int s0_ = csr[e0 + j + 0], s1_ = csr[e0 + j + 1];
    int s2_ = csr[e0 + j + 2], s3_ = csr[e0 + j + 3];
    int s4_ = csr[e0 + j + 4], s5_ = csr[e0 + j + 5];
    int s6_ = csr[e0 + j + 6], s7_ = csr[e0 + j + 7];
    float lg0 = ss[s0_ * 8 + h2], lg1 = ss[s1_ * 8 + h2];
    float lg2 = ss[s2_ * 8 + h2], lg3 = ss[s3_ * 8 + h2];
    float lg4 = ss[s4_ * 8 + h2], lg5 = ss[s5_ * 8 + h2];
    float lg6 = ss[s6_ * 8 + h2], lg7 = ss[s7_ * 8 + h2];
    ushort4 v0 = *(const ushort4*)&xsb[(size_t)s0_ * HID + lane * 4];
    ushort4 v1 = *(const ushort4*)&xsb[(size_t)s1_ * HID + lane * 4];
    ushort4 v2 = *(const ushort4*)&xsb[(size_t)s2_ * HID + lane * 4];
    ushort4 v3 = *(const ushort4*)&xsb[(size_t)s3_ * HID + lane * 4];
    ushort4 v4 = *(const ushort4*)&xsb[(size_t)s4_ * HID + lane * 4];
    ushort4 v5 = *(const ushort4*)&xsb[(size_t)s5_ * HID + lane * 4];
    ushort4 v6 = *(const ushort4*)&xsb[(size_t)s6_ * HID + lane * 4];
    ushort4 v7 = *(const ushort4*)&xsb[(size_t)s7_ * HID + lane * 4];
    CONV_EDGE(0) CONV_EDGE(1) CONV_EDGE(2) CONV_EDGE(3)
    CONV_EDGE(4) CONV_EDGE(5) CONV_EDGE(6) CONV_EDGE(7)
  }
  for (; j + 2 <= ne; j += 2) {
    int s0_ = csr[e0 + j + 0], s1_ = csr[e0 + j + 1];
    float lg0 = ss[s0_ * 8 + h2], lg1 = ss[s1_ * 8 + h2];
    ushort4 v0 = *(const ushort4*)&xsb[(size_t)s0_ * HID + lane * 4];
    ushort4 v1 = *(const ushort4*)&xsb[(size_t)s1_ * HID + lane * 4];
    CONV_EDGE(0) CONV_EDGE(1)
  }
  if (j < ne) {
    int s0_ = csr[e0 + j];
    float lg0 = ss[s0_ * 8 + h2];
    ushort4 v0 = *(const ushort4*)&xsb[(size_t)s0_ * HID + lane * 4];
    CONV_EDGE(0)
  }
  const float inv = 1.f / (den + 1e-16f);
  ushort4 o;
  o.x = (ush)bfr(fmaxf(a0 * inv, 0.f));
  o.y = (ush)bfr(fmaxf(a1 * inv, 0.f));
  o.z = (ush)bfr(fmaxf(a2 * inv, 0.f));
  o.w = (ush)bfr(fmaxf(a3 * inv, 0.f));
  *(ushort4*)&zall[(size_t)grow * HID + lane * 4] = o;
}

// ---------------------------------------------------------------------------
// Semantic scores v10 (R19, unchanged — B-resident+pinned, A via shared LDS).
// ---------------------------------------------------------------------------
__global__ __launch_bounds__(256, 2) void semscore_kernel(
    const ush* __restrict__ zall, const ush* __restrict__ wkT,
    const float* __restrict__ bk, const float* __restrict__ q,
    float* __restrict__ parts)
{
  __shared__ ush As[2][16 * 256];
  __shared__ float red[4];
  const int bid = blockIdx.x;
  const int mat = bid / SMQ;
  const int rb  = bid % SMQ;
  const ush* zsrc = zall + (size_t)mat * N * HID;
  const int t = threadIdx.x;
  const int w = t >> 6, l = t & 63;
  const int lrow = l & 15, kgrp = l >> 4;
  const int row0 = rb * 512;

  u32 B[4][8][4];
  float bkv[4], qv[4];
#pragma unroll
  for (int j = 0; j < 4; ++j) {
    const int col = (w * 4 + j) * 16 + lrow;
    bkv[j] = bk[col];
    qv[j] = q[col];
#pragma unroll
    for (int ks = 0; ks < 8; ++ks) {
      uint4 v = *(const uint4*)&wkT[(size_t)col * HID + ks * 32 + kgrp * 8];
      B[j][ks][0] = v.x; B[j][ks][1] = v.y; B[j][ks][2] = v.z; B[j][ks][3] = v.w;
      asm volatile("" : "+v"(B[j][ks][0]), "+v"(B[j][ks][1]),
                        "+v"(B[j][ks][2]), "+v"(B[j][ks][3]));
    }
  }

  auto stage = [&](int buf, int rt) {
#pragma unroll
    for (int i = 0; i < 2; ++i) {
      int q16 = i * 256 + t;
      int r = q16 >> 5;
      int c = (q16 & 31) ^ (r & 7);
      int gr = row0 + rt * 16 + r;
      if (gr >= N) gr = N - 1;
      gll16(&zsrc[(size_t)gr * HID + c * 8], &As[buf][(i * 256 + w * 64) * 8]);
    }
  };

  float s = 0.f;
  stage(0, 0);
  int cur = 0;
  for (int rt = 0; rt < 32; ++rt) {
    if (rt < 31) {
      stage(cur ^ 1, rt + 1);
      WAITK("2");
    } else {
      WAITK("0");
    }
    f32x4 acc[4];
    const f32x4 zz = {0.f, 0.f, 0.f, 0.f};
#pragma unroll
    for (int j = 0; j < 4; ++j) acc[j] = zz;
#pragma unroll
    for (int ks = 0; ks < 8; ++ks) {
      const int ch = (ks * 4 + kgrp) ^ (lrow & 7);
      bf16x8 Af = *(const bf16x8*)&As[cur][(lrow * 32 + ch) * 8];
#pragma unroll
      for (int j = 0; j < 4; ++j) {
        union { u32 u[4]; bf16x8 v; } bb;
        bb.u[0] = B[j][ks][0]; bb.u[1] = B[j][ks][1];
        bb.u[2] = B[j][ks][2]; bb.u[3] = B[j][ks][3];
        acc[j] = __builtin_amdgcn_mfma_f32_16x16x32_bf16(Af, bb.v, acc[j], 0, 0, 0);
      }
    }
#pragma unroll
    for (int j = 0; j < 4; ++j)
#pragma unroll
      for (int i = 0; i < 4; ++i) {
        int gr = row0 + rt * 16 + kgrp * 4 + i;
        if (gr < N) s += tanh_fast(acc[j][i] + bkv[j]) * qv[j];
      }
    __syncthreads();
    cur ^= 1;
  }

#pragma unroll
  for (int off = 1; off < 64; off <<= 1) s += __shfl_xor(s, off);
  if (l == 0) red[w] = s;
  __syncthreads();
  if (t == 0) parts[bid] = red[0] + red[1] + red[2] + red[3];
}

// ---------------------------------------------------------------------------
// Final (R19 version — partial-reduce + softmax inline, unpinned B).
// ---------------------------------------------------------------------------
__global__ __launch_bounds__(256, 2) void final_kernel(
    const ush* __restrict__ zbu0, const ush* __restrict__ zbu1,
    const ush* __restrict__ zbi0, const ush* __restrict__ zbi1,
    const float* __restrict__ parts, const ush* __restrict__ wlT,
    const float* __restrict__ bl, float* __restrict__ out)
{
  __shared__ float redA[4], redB[4], attn[2];
  const int bid = blockIdx.x;
  const int side = bid >= FB;
  const ush* z0 = side ? zbi0 : zbu0;
  const ush* z1 = side ? zbi1 : zbu1;
  float* op = out + (size_t)side * N * OUTD;
  const int t = threadIdx.x;
  const int w = t >> 6, l = t & 63;

  const float* p0 = parts + (size_t)(side * 2) * SMQ;
  const float* p1 = p0 + SMQ;
  float s0 = 0.f, s1 = 0.f;
  for (int i = t; i < SMQ; i += 256) { s0 += p0[i]; s1 += p1[i]; }
#pragma unroll
  for (int off = 1; off < 64; off <<= 1) {
    s0 += __shfl_xor(s0, off);
    s1 += __shfl_xor(s1, off);
  }
  if (l == 0) { redA[w] = s0; redB[w] = s1; }
  __syncthreads();
  if (t == 0) {
    const float inv_n = 1.f / (float)N;
    float r0 = (redA[0] + redA[1] + redA[2] + redA[3]) * inv_n;
    float r1 = (redB[0] + redB[1] + redB[2] + redB[3]) * inv_n;
    float mm = fmaxf(r0, r1);
    float e0 = __expf(r0 - mm), e1 = __expf(r1 - mm);
    attn[0] = e0 / (e0 + e1);
    attn[1] = e1 / (e0 + e1);
  }
  __syncthreads();
  const float a0 = attn[0], a1 = attn[1];

  const int lrow = l & 15, kgrp = l >> 4;
  const int base = (bid - side * FB) * 64;
  int arow = base + w * 16 + lrow;
  if (arow >= N) arow = N - 1;

  bf16x8 Af[8];
#pragma unroll
  for (int ks = 0; ks < 8; ++ks) {
    const ush* pz0 = &z0[(size_t)arow * HID + ks * 32 + kgrp * 8];
    const ush* pz1 = &z1[(size_t)arow * HID + ks * 32 + kgrp * 8];
    ushort4 u0a = *(const ushort4*)pz0, u0b = *(const ushort4*)(pz0 + 4);
    ushort4 u1a = *(const ushort4*)pz1, u1b = *(const ushort4*)(pz1 + 4);
    union { u32 u[4]; bf16x8 v; } c;
    c.u[0] = pk2(a0 * bf2f(u0a.x) + a1 * bf2f(u1a.x),
                 a0 * bf2f(u0a.y) + a1 * bf2f(u1a.y));
    c.u[1] = pk2(a0 * bf2f(u0a.z) + a1 * bf2f(u1a.z),
                 a0 * bf2f(u0a.w) + a1 * bf2f(u1a.w));
    c.u[2] = pk2(a0 * bf2f(u0b.x) + a1 * bf2f(u1b.x),
                 a0 * bf2f(u0b.y) + a1 * bf2f(u1b.y));
    c.u[3] = pk2(a0 * bf2f(u0b.z) + a1 * bf2f(u1b.z),
                 a0 * bf2f(u0b.w) + a1 * bf2f(u1b.w));
    Af[ks] = c.v;
  }

#pragma unroll
  for (int nt = 0; nt < 4; ++nt) {
    const int col = nt * 16 + lrow;
    f32x4 acc = {0.f, 0.f, 0.f, 0.f};
#pragma unroll
    for (int ks = 0; ks < 8; ++ks) {
      bf16x8 Bf = *(const bf16x8*)&wlT[(size_t)col * HID + ks * 32 + kgrp * 8];
      acc = __builtin_amdgcn_mfma_f32_16x16x32_bf16(Af[ks], Bf, acc, 0, 0, 0);
    }
    const float bb = bl[col];
#pragma unroll
    for (int i = 0; i < 4; ++i) {
      int gr = base + w * 16 + kgrp * 4 + i;
      if (gr < N) op[(size_t)gr * OUTD + col] = acc[i] + bb;
    }
  }
}

// ---------------------------------------------------------------------------
extern "C" void kernel_launch(void* const* d_in, const int* in_sizes, int n_in,
                              void* d_out, int out_size, void* d_ws, size_t ws_size,
                              hipStream_t stream)
{
  const float* x_user = (const float*)d_in[0];
  const float* x_item = (const float*)d_in[1];
  const int*   e_ui   = (const int*)d_in[2];
  const int*   e_iu   = (const int*)d_in[3];
  const int*   e_uu   = (const int*)d_in[4];
  const int*   e_ii   = (const int*)d_in[5];
  const float* Wp_u   = (const float*)d_in[6];
  const float* bp_u   = (const float*)d_in[7];
  const float* Wp_i   = (const float*)d_in[8];
  const float* bp_i   = (const float*)d_in[9];
  const float* as_ui  = (const float*)d_in[10];
  const float* ad_ui  = (const float*)d_in[11];
  const float* as_iu  = (const float*)d_in[12];
  const float* ad_iu  = (const float*)d_in[13];
  const float* as_uu  = (const float*)d_in[14];
  const float* ad_uu  = (const float*)d_in[15];
  const float* as_ii  = (const float*)d_in[16];
  const float* ad_ii  = (const float*)d_in[17];
  const float* Wk     = (const float*)d_in[18];
  const float* bk     = (const float*)d_in[19];
  const float* q      = (const float*)d_in[20];
  const float* Wl     = (const float*)d_in[21];
  const float* bl     = (const float*)d_in[22];

  const size_t NH = (size_t)N * HID;
  const size_t WT = 65536 + 2 * 32768 + 16384;
  size_t need = (8 * (size_t)N8 + 4 * (size_t)SMQ + 4) * 4
              + (6 * NH + WT) * 2
              + ((size_t)8 * N + (size_t)NBT * BCAP + NBT) * 4;
  if (ws_size < need) {
    hipMemsetAsync(d_out, 0x7f, (size_t)out_size * sizeof(float), stream);
    return;
  }
  float* su = (float*)d_ws;
  float* si = su + 4 * (size_t)N8;
  float* parts = si + 4 * (size_t)N8;
  ush* zbu0 = (ush*)(parts + 4 * (size_t)SMQ + 4);
  ush* zbu1 = zbu0 + NH;
  ush* zbi0 = zbu1 + NH;
  ush* zbi1 = zbi0 + NH;
  ush* hub  = zbi1 + NH;
  ush* hib  = hub + NH;
  ush* wkT  = hib + NH;
  ush* wpTu = wkT + 65536;
  ush* wpTi = wpTu + 32768;
  ush* wlT  = wpTi + 32768;
  int* count  = (int*)(wlT + 16384);
  int* start  = count + NTOT;
  int* bcnt   = start + NTOT;
  int* csr    = bcnt + NBT;
  u32* bstage = (u32*)zbu0;     // 16.0 MB <= 25.6 MB (dead until conv)

  // 1. weight transposes + zero bcnt
  tran_kernel<<<576, 256, 0, stream>>>(Wk, Wp_u, Wp_i, Wl, wkT, wpTu, wpTi, wlT,
                                       bcnt);
  // 2. projections + fused node scores (both types)
  proj_kernel<<<2 * FB, 256, 0, stream>>>(x_user, x_item, wpTu, wpTi, bp_u, bp_i,
                                          ad_iu, as_uu, ad_uu, as_ui,
                                          as_iu, ad_ui, as_ii, ad_ii,
                                          hub, hib, su, si);
  // 3. multisplit into fixed-capacity buckets (single edge pass)
  scat2_kernel<<<4 * NB1, 256, 0, stream>>>(e_iu, e_iu + E, e_uu, e_uu + E,
                                            e_ui, e_ui + E, e_ii, e_ii + E,
                                            bcnt, bstage);
  // 4. fused fine count + scan + csr fill
  fillb_kernel<<<NBT, 256, 0, stream>>>(bstage, bcnt, start, count, csr);
  // 5. all 4 relation convs in ONE launch
  conv_kernel<<<NTOT / 4, 256, 0, stream>>>(hub, hib, su, si, csr, start, count,
                                            zbu0);
  // 6. semantic attention partials (B-resident, A via shared LDS)
  semscore_kernel<<<4 * SMQ, 256, 0, stream>>>(zbu0, wkT, bk, q, parts);
  // 7. final linear (partial-reduce + softmax inline)
  final_kernel<<<2 * FB, 256, 0, stream>>>(zbu0, zbu1, zbi0, zbi1, parts, wlT, bl,
                                           (float*)d_out);
}